// Round 8
// baseline (4306.364 us; speedup 1.0000x reference)
//
#include <hip/hip_runtime.h>

#define DEVINL static __device__ __forceinline__
// Same-wave LDS ordering: compiler reorder fence only (validated r10/r12).
#define CFENCE() asm volatile("" ::: "memory")

typedef float v2f __attribute__((ext_vector_type(2)));

DEVINL v2f mk2(float a, float b) { v2f r; r.x = a; r.y = b; return r; }
DEVINL v2f pkfma(v2f a, v2f b, v2f c) { return __builtin_elementwise_fma(a, b, c); }

constexpr float KE = 2.885390081777927f;   // 2*log2(e)

#if __has_builtin(__builtin_amdgcn_exp2f)
DEVINL float exp2_fast(float x) { return __builtin_amdgcn_exp2f(x); }
#else
DEVINL float exp2_fast(float x) { return __expf(x * 0.6931471805599453f); }
#endif

// tanh(x) with t = x*2*log2(e) pre-folded into weights: 1 - 2/(2^t+1).
DEVINL float tanh_pre(float t) {
  float e = exp2_fast(t);
  return 1.0f - 2.0f * __builtin_amdgcn_rcpf(e + 1.0f);
}

template <int CTRL>
DEVINL float dpp_add(float v) {
  int t = __builtin_amdgcn_update_dpp(0, __float_as_int(v), CTRL, 0xF, 0xF, true);
  return v + __int_as_float(t);
}
DEVINL float rlane(float v, int l) {
  return __int_as_float(__builtin_amdgcn_readlane(__float_as_int(v), l));
}
// 4-stage row-local DPP partial sums; 32-sums via readlane pairs
// (commutative pair-add, bit-identical to row_bcast15 variant; validated R2).
DEVINL float psum4(float v) {
  v = dpp_add<0xB1>(v);    // quad_perm [1,0,3,2]
  v = dpp_add<0x4E>(v);    // quad_perm [2,3,0,1]
  v = dpp_add<0x141>(v);   // row_half_mirror
  v = dpp_add<0x140>(v);   // row_mirror -> 16-sums per row
  return v;
}

constexpr int TT = 256;

// ---- weight transpose: one 64-thread block fills the per-lane table ----
// Per lane ln (j = ln&31, hi = ln>=32), contiguous 96-float block:
//  [0..31]  W1 column j of (hi? r2W1 : r1W1), pairs (2k,2k+1), *KE
//  [32..55] W0C per-half z/z4 mapping (12 v2f), *KE
//  [56..71] W1C per-half k-slice (8 v2f), *KE
//  [72..73] WX (r3W0 rows 14,15), *KE
//  [74..80] scalars: w0K,b0K,b1K,w2sc,b0CK,b1CK,w2C02
//  tail wt[6144..6146]: b2sA, b2sB, b2Cs (wave-uniform)
__global__ void wtrans_kernel(
    const float* __restrict__ r1W0, const float* __restrict__ r1b0,
    const float* __restrict__ r1W1, const float* __restrict__ r1b1,
    const float* __restrict__ r1W2, const float* __restrict__ r1b2,
    const float* __restrict__ r2W0, const float* __restrict__ r2b0,
    const float* __restrict__ r2W1, const float* __restrict__ r2b1,
    const float* __restrict__ r2W2, const float* __restrict__ r2b2,
    const float* __restrict__ r3W0, const float* __restrict__ r3b0,
    const float* __restrict__ r3W1, const float* __restrict__ r3b1,
    const float* __restrict__ r3W2, const float* __restrict__ r3b2,
    float* __restrict__ wt)
{
  const int ln = threadIdx.x;
  const int j = ln & 31;
  const bool hi = ln >= 32;
  float* d = wt + ln * 96;
  const float* W1p = hi ? r2W1 : r1W1;
#pragma unroll
  for (int k = 0; k < 16; ++k) {
    d[2 * k]     = W1p[(2 * k) * 32 + j] * KE;
    d[2 * k + 1] = W1p[(2 * k + 1) * 32 + j] * KE;
  }
#pragma unroll
  for (int m = 0; m < 12; ++m) {
    int r = (hi && m >= 1 && m <= 7) ? (2 * m - 2) : (2 * m);
    float a = r3W0[r * 32 + j] * KE;
    float bb = r3W0[(r + 1) * 32 + j] * KE;
    if (hi && m == 0) { a = 0.f; bb = 0.f; }
    d[32 + 2 * m] = a;
    d[33 + 2 * m] = bb;
  }
  const int kbase = hi ? 16 : 0;
#pragma unroll
  for (int k = 0; k < 8; ++k) {
    d[56 + 2 * k]     = r3W1[(kbase + 2 * k) * 32 + j] * KE;
    d[57 + 2 * k + 0] = r3W1[(kbase + 2 * k + 1) * 32 + j] * KE;
  }
  d[72] = r3W0[14 * 32 + j] * KE;
  d[73] = r3W0[15 * 32 + j] * KE;
  d[74] = (hi ? r2W0 : r1W0)[j] * KE;
  d[75] = (hi ? r2b0 : r1b0)[j] * KE;
  d[76] = (hi ? r2b1 : r1b1)[j] * KE;
  d[77] = (hi ? r2W2 : r1W2)[j] * (hi ? 0.2f : 0.3f);
  d[78] = r3b0[j] * KE;
  d[79] = r3b1[j] * KE;
  d[80] = r3W2[j] * 0.2f;
  d[81] = 0.f; d[82] = 0.f; d[83] = 0.f;
  d[84] = 0.f; d[85] = 0.f; d[86] = 0.f; d[87] = 0.f;
  d[88] = 0.f; d[89] = 0.f; d[90] = 0.f; d[91] = 0.f;
  d[92] = 0.f; d[93] = 0.f; d[94] = 0.f; d[95] = 0.f;
  if (ln == 0) {
    wt[64 * 96 + 0] = r1b2[0] * 0.3f;                // b2sA
    wt[64 * 96 + 1] = r2b2[0] * 0.2f;                // b2sB
    wt[64 * 96 + 2] = r3b2[0] * 0.2f - 0.05f;        // b2Cs (folds -F/V*0.5)
  }
}

// wave = 1 batch element; lanes 0-31 = net r1 / z duties, 32-63 = r2 / z4.
// grid 4096 -> 16 waves/CU = 4 waves/EU (validated R1 structure).
// All weights read from the lane-contiguous wt table: every remat across a
// CFENCE is one global_load_dwordx4 (vmcnt — overlaps the h-row lgkmcnt).
__global__ __attribute__((amdgpu_flat_work_group_size(64, 64)))
__attribute__((amdgpu_waves_per_eu(4, 4))) void reac_kernel(
    const float* __restrict__ useq,   // [B][T] f32
    const float* __restrict__ xz0,    // [B][26] f32
    const float* __restrict__ wt,     // transposed weight table
    float2* __restrict__ out)         // [B][T] -> (x0,x1) f32
{
  const int lane = threadIdx.x;
  const int j = lane & 31;
  const bool hi = lane >= 32;      // high half = r2 net / z4 duties
  const int b = blockIdx.x;
  const int xaddr = ((lane ^ 32) << 2);   // ds_bpermute partner address

  auto xchg = [&](float v) -> float {
    return __int_as_float(__builtin_amdgcn_ds_bpermute(xaddr, __float_as_int(v)));
  };

  const float* wp = wt + lane * 96;
  const float4* wp4 = (const float4*)wp;

  // Per-lane scalars (cheap x4 remats if the allocator drops them).
  float4 sc0 = wp4[18];   // WX.x WX.y w0K b0K
  float4 sc1 = wp4[19];   // b1K w2sc b0CK b1CK
  const float w2C02 = wp[80];
  const float b2sA = wt[6144];
  const float b2sB = wt[6145];
  const float b2Cs = wt[6146];
  const int kbase = hi ? 16 : 0;   // only used for hR3 indexing now

  __shared__ __align__(16) float zs[24];      // z state
  __shared__ __align__(16) float h12[2][32];  // [net][neuron] broadcast
  __shared__ __align__(16) float hR3[3][32];  // [eval: z,z23,z4][neuron]

  float x0 = xz0[b * 26 + 0];
  float x1 = xz0[b * 26 + 1];
  if (!hi && j < 24) zs[j] = xz0[b * 26 + 2 + j];
  CFENCE();

  // 32-wide dot vs LDS h-row; weights streamed as float4 (wp4[0..7]).
  auto dot32W = [&](const float* hrow, float bias) -> float {
    const float4* hp = (const float4*)hrow;
    v2f a0 = mk2(bias, 0.f), a1 = mk2(0.f, 0.f);
    v2f a2 = mk2(0.f, 0.f), a3 = mk2(0.f, 0.f);
#pragma unroll
    for (int q = 0; q < 8; q += 2) {
      float4 x = hp[q], y = hp[q + 1];
      float4 wa = wp4[q], wb = wp4[q + 1];
      a0 = pkfma(mk2(x.x, x.y), mk2(wa.x, wa.y), a0);
      a1 = pkfma(mk2(x.z, x.w), mk2(wa.z, wa.w), a1);
      a2 = pkfma(mk2(y.x, y.y), mk2(wb.x, wb.y), a2);
      a3 = pkfma(mk2(y.z, y.w), mk2(wb.z, wb.w), a3);
    }
    v2f s = (a0 + a1) + (a2 + a3);
    return s.x + s.y;
  };
  // 16-wide partial dot (k-split r3 layer 1); weights wp4[14..17].
  auto pdot16W = [&](const float* hrow) -> float {
    const float4* hp = (const float4*)hrow;
    v2f a0 = mk2(0.f, 0.f), a1 = mk2(0.f, 0.f);
    float4 x = hp[0], y = hp[1];
    float4 wa = wp4[14], wb = wp4[15];
    a0 = pkfma(mk2(x.x, x.y), mk2(wa.x, wa.y), a0);
    a1 = pkfma(mk2(x.z, x.w), mk2(wa.z, wa.w), a1);
    a0 = pkfma(mk2(y.x, y.y), mk2(wb.x, wb.y), a0);
    a1 = pkfma(mk2(y.z, y.w), mk2(wb.z, wb.w), a1);
    x = hp[2]; y = hp[3];
    wa = wp4[16]; wb = wp4[17];
    a0 = pkfma(mk2(x.x, x.y), mk2(wa.x, wa.y), a0);
    a1 = pkfma(mk2(x.z, x.w), mk2(wa.z, wa.w), a1);
    a0 = pkfma(mk2(y.x, y.y), mk2(wb.x, wb.y), a0);
    a1 = pkfma(mk2(y.z, y.w), mk2(wb.z, wb.w), a1);
    v2f s = a0 + a1;
    return s.x + s.y;
  };
  // r3 layer-0 over zs: low half accumulates A(z), high half A(z4)-prefix
  // (per-half mapping baked into the table). Weights wp4[8..13].
  auto r3_l0 = [&](v2f& aaO, v2f& abO) {
    const float4* zp = (const float4*)zs;
    float4 z0 = zp[0], z1 = zp[1], z2 = zp[2], z3 = zp[3];
    float4 u0 = zp[4], u1 = zp[5];
    float4 w8 = wp4[8], w9 = wp4[9], w10 = wp4[10];
    float4 w11 = wp4[11], w12 = wp4[12], w13 = wp4[13];
    v2f aa = mk2(sc1.z, 0.f), ab = mk2(0.f, 0.f);   // sc1.z = b0CK
    aa = pkfma(mk2(z0.x, z0.y), mk2(w8.x, w8.y), aa);
    ab = pkfma(mk2(z0.z, z0.w), mk2(w8.z, w8.w), ab);
    aa = pkfma(mk2(z1.x, z1.y), mk2(w9.x, w9.y), aa);
    ab = pkfma(mk2(z1.z, z1.w), mk2(w9.z, w9.w), ab);
    aa = pkfma(mk2(z2.x, z2.y), mk2(w10.x, w10.y), aa);
    ab = pkfma(mk2(z2.z, z2.w), mk2(w10.z, w10.w), ab);
    aa = pkfma(mk2(z3.x, z3.y), mk2(w11.x, w11.y), aa);
    ab = pkfma(mk2(z3.z, z3.w), mk2(w11.z, w11.w), ab);
    aa = pkfma(mk2(u0.x, u0.y), mk2(w12.x, w12.y), aa);
    ab = pkfma(mk2(u0.z, u0.w), mk2(w12.z, w12.w), ab);
    aa = pkfma(mk2(u1.x, u1.y), mk2(w13.x, w13.y), aa);
    ab = pkfma(mk2(u1.z, u1.w), mk2(w13.z, w13.w), ab);
    aaO = aa; abO = ab;
  };
  auto rc1_eval = [&]() -> float {
    float p0 = pdot16W(&hR3[0][kbase]);
    float o0 = p0 + xchg(p0) + sc1.w;                 // + b1CK
    float v = psum4(tanh_pre(o0) * w2C02);
    return (rlane(v, 15) + rlane(v, 31)) + b2Cs;
  };
  auto net_pre = [&](float sxv, float syv) -> float {
    float sv = hi ? syv : sxv;
    return tanh_pre(fmaf(sv, sc0.z, sc0.w));          // w0K, b0K
  };
  auto net_post = [&](float sxv, float syv, float rc_m05, float CafF,
                      float& kx, float& ky) {
    float a = dot32W(&h12[hi][0], sc1.x);             // bias b1K
    float v = psum4(tanh_pre(a) * sc1.y);             // * w2sc
    float ra = (rlane(v, 15) + rlane(v, 31)) + b2sA;  // r1 (uniform)
    float rb = (rlane(v, 47) + rlane(v, 63)) + b2sB;  // r2 (uniform)
    float dCa = fmaf(-0.03f, sxv, CafF) - ra;
    float dCb = fmaf(-0.02f, syv, fmaf(-3.0f, rb, ra) + rc_m05);
    kx = dCa * (1.0f / 0.3f);
    ky = dCb * (1.0f / 0.2f);
  };

  // ---- prologue: pipeline state for t=0 ----
  v2f aa4, ab4;            // carried A(z4)-prefix accumulators (high half)
  float Az;                // carried A(z_t) (low half)
  r3_l0(aa4, ab4);
  {
    v2f s = aa4 + ab4;
    Az = s.x + s.y;
    float h0 = tanh_pre(Az);
    CFENCE();
    if (!hi) hR3[0][j] = h0;
    CFENCE();
  }
  float rc1 = rc1_eval();

  float u = useq[b * TT];

  for (int t = 0; t < TT; ++t) {
    int tn = (t < TT - 1) ? (t + 1) : t;
    float u_nxt = useq[b * TT + tn];   // prefetch, consumed next iter
    float CafF = fmaf(u, 0.05f, 0.05f);

    if (lane == 0) out[b * TT + t] = make_float2(x0, x1);

    // R0: complete z4 eval (1 pkfma) + z23 via layer-0 linearity; stage-1 h.
    ab4 = pkfma(mk2(x0, x1), mk2(sc0.x, sc0.y), ab4);   // WXv
    v2f s4v = aa4 + ab4;
    float A4 = s4v.x + s4v.y;                 // A(z4), high lanes
    float Apart = xchg(hi ? A4 : Az);
    float targ = hi ? A4 : (0.5f * (Az + Apart));   // z23 on low half
    float hh = tanh_pre(targ);
    float h1 = net_pre(x0, x1);
    CFENCE();
    // R1: LDS broadcasts
    hR3[1 + hi][j] = hh;        // low -> h(z23), high -> h(z4)
    h12[hi][j] = h1;
    CFENCE();
    // R2: head finish (rc23, rc4) || stage-1 finish || stage-2 layer-0
    float p1 = pdot16W(&hR3[1][kbase]);
    float p2 = pdot16W(&hR3[2][kbase]);
    float o1 = p1 + xchg(p1) + sc1.w;
    float o2 = p2 + xchg(p2) + sc1.w;
    float vv = psum4(tanh_pre(hi ? o2 : o1) * w2C02);
    float rc23 = (rlane(vv, 15) + rlane(vv, 31)) + b2Cs;
    float rc4  = (rlane(vv, 47) + rlane(vv, 63)) + b2Cs;
    float kx1, ky1;
    net_post(x0, x1, rc1, CafF, kx1, ky1);
    float sx2 = fmaf(kx1, 0.5f, x0), sy2 = fmaf(ky1, 0.5f, x1);
    float h2 = net_pre(sx2, sy2);
    CFENCE();
    // R3
    h12[hi][j] = h2;
    CFENCE();
    // R4a: stage-2 finish || z-shift (scalar reads then masked write)
    float kx2, ky2;
    net_post(sx2, sy2, rc23, CafF, kx2, ky2);
    {
      // zplus = [zs[2:16], x0, x1, zs[17:24], u]
      int src = (j < 14) ? (j + 2) : ((j < 23) ? (j + 1) : 0);
      float zread = zs[src];
      float znew = (j == 14) ? x0 : ((j == 15) ? x1 : ((j == 23) ? u : zread));
      CFENCE();                  // zs reads complete before the write
      if ((!hi) && (j < 24)) zs[j] = znew;
    }
    CFENCE();
    // R4b: r3 layer-0 for t+1 (reads shifted zs) || stage-3 layer-0
    r3_l0(aa4, ab4);
    {
      v2f sv2 = aa4 + ab4;
      Az = sv2.x + sv2.y;                  // A(z_{t+1}) on low lanes
      float h0n = tanh_pre(Az);
      if (!hi) hR3[0][j] = h0n;            // h(z_{t+1})
    }
    float sx3 = fmaf(kx2, 0.5f, x0), sy3 = fmaf(ky2, 0.5f, x1);
    float h3 = net_pre(sx3, sy3);
    CFENCE();
    // R5
    h12[hi][j] = h3;
    CFENCE();
    // R6: stage-3 finish || rc1 for t+1 || stage-4 layer-0
    float kx3, ky3;
    net_post(sx3, sy3, rc23, CafF, kx3, ky3);
    rc1 = rc1_eval();
    float sx4 = x0 + kx3, sy4 = x1 + ky3;
    float h4 = net_pre(sx4, sy4);
    CFENCE();
    // R7
    h12[hi][j] = h4;
    CFENCE();
    // R8: stage-4 finish, state update
    float kx4, ky4;
    net_post(sx4, sy4, rc4, CafF, kx4, ky4);
    x0 += (kx1 + 2.0f * (kx2 + kx3) + kx4) * (1.0f / 6.0f);
    x1 += (ky1 + 2.0f * (ky2 + ky3) + ky4) * (1.0f / 6.0f);
    u = u_nxt;
    CFENCE();
  }
}

extern "C" void kernel_launch(void* const* d_in, const int* in_sizes, int n_in,
                              void* d_out, int out_size, void* d_ws, size_t ws_size,
                              hipStream_t stream) {
  const float* p[20];
  for (int i = 0; i < 20; ++i) p[i] = (const float*)d_in[i];
  float* wtab = (float*)d_ws;
  wtrans_kernel<<<dim3(1), dim3(64), 0, stream>>>(
      p[2], p[3], p[4], p[5], p[6], p[7], p[8], p[9], p[10], p[11],
      p[12], p[13], p[14], p[15], p[16], p[17], p[18], p[19], wtab);
  reac_kernel<<<dim3(4096), dim3(64), 0, stream>>>(
      p[0], p[1], wtab, (float2*)d_out);
}

// Round 9
// 1469.441 us; speedup vs baseline: 2.9306x; 2.9306x over previous
//
#include <hip/hip_runtime.h>

#define DEVINL static __device__ __forceinline__
// Same-wave LDS ordering: compiler reorder fence only (validated r10/r12).
#define CFENCE() asm volatile("" ::: "memory")

typedef float v2f __attribute__((ext_vector_type(2)));

DEVINL v2f mk2(float a, float b) { v2f r; r.x = a; r.y = b; return r; }
DEVINL v2f pkfma(v2f a, v2f b, v2f c) { return __builtin_elementwise_fma(a, b, c); }

constexpr float KE = 2.885390081777927f;   // 2*log2(e)

#if __has_builtin(__builtin_amdgcn_exp2f)
DEVINL float exp2_fast(float x) { return __builtin_amdgcn_exp2f(x); }
#else
DEVINL float exp2_fast(float x) { return __expf(x * 0.6931471805599453f); }
#endif

// tanh(x) with t = x*2*log2(e) pre-folded into weights: 1 - 2/(2^t+1).
DEVINL float tanh_pre(float t) {
  float e = exp2_fast(t);
  return 1.0f - 2.0f * __builtin_amdgcn_rcpf(e + 1.0f);
}

template <int CTRL>
DEVINL float dpp_add(float v) {
  int t = __builtin_amdgcn_update_dpp(0, __float_as_int(v), CTRL, 0xF, 0xF, true);
  return v + __int_as_float(t);
}
DEVINL float rlane(float v, int l) {
  return __int_as_float(__builtin_amdgcn_readlane(__float_as_int(v), l));
}
// 4-stage row-local DPP partial sums; 32-sums via readlane pairs
// (commutative pair-add, bit-identical to row_bcast15 variant; validated R2).
DEVINL float psum4(float v) {
  v = dpp_add<0xB1>(v);    // quad_perm [1,0,3,2]
  v = dpp_add<0x4E>(v);    // quad_perm [2,3,0,1]
  v = dpp_add<0x141>(v);   // row_half_mirror
  v = dpp_add<0x140>(v);   // row_mirror -> 16-sums per row
  return v;
}

constexpr int TT = 256;

// ---- weight transpose into a COALESCED [slot][lane] float4 table ----
// Lane ln (j=ln&31, hi=ln>=32) reads float4 slot p at wt[(p*64+ln)*4]:
//  p 0..7  : W1 rows (4p..4p+3) col j of (hi? r2W1 : r1W1), *KE
//  p 8..13 : W0C pairs (2p-16, 2p-15) with the per-half z/z4 row mapping
//  p 14..17: W1C pairs, per-half k-slice (kbase = hi?16:0)
//  p 18    : (WX.x, WX.y, w0K, b0K)    p 19: (b1K, w2sc, b0CK, b1CK)
//  p 20    : (w2C02, 0, 0, 0)
//  tail floats [5376..5378]: b2sA, b2sB, b2Cs (wave-uniform)
__global__ void wtrans_kernel(
    const float* __restrict__ r1W0, const float* __restrict__ r1b0,
    const float* __restrict__ r1W1, const float* __restrict__ r1b1,
    const float* __restrict__ r1W2, const float* __restrict__ r1b2,
    const float* __restrict__ r2W0, const float* __restrict__ r2b0,
    const float* __restrict__ r2W1, const float* __restrict__ r2b1,
    const float* __restrict__ r2W2, const float* __restrict__ r2b2,
    const float* __restrict__ r3W0, const float* __restrict__ r3b0,
    const float* __restrict__ r3W1, const float* __restrict__ r3b1,
    const float* __restrict__ r3W2, const float* __restrict__ r3b2,
    float* __restrict__ wt)
{
  const int ln = threadIdx.x;
  const int j = ln & 31;
  const bool hi = ln >= 32;
  const float* W1p = hi ? r2W1 : r1W1;
#pragma unroll
  for (int p = 0; p < 8; ++p) {
    float* d = wt + (p * 64 + ln) * 4;
    d[0] = W1p[(4 * p + 0) * 32 + j] * KE;
    d[1] = W1p[(4 * p + 1) * 32 + j] * KE;
    d[2] = W1p[(4 * p + 2) * 32 + j] * KE;
    d[3] = W1p[(4 * p + 3) * 32 + j] * KE;
  }
#pragma unroll
  for (int p = 0; p < 6; ++p) {   // W0C pairs (m = 2p, 2p+1)
    float* d = wt + ((8 + p) * 64 + ln) * 4;
#pragma unroll
    for (int e = 0; e < 2; ++e) {
      int m = 2 * p + e;
      int r = (hi && m >= 1 && m <= 7) ? (2 * m - 2) : (2 * m);
      float a = r3W0[r * 32 + j] * KE;
      float bb = r3W0[(r + 1) * 32 + j] * KE;
      if (hi && m == 0) { a = 0.f; bb = 0.f; }
      d[2 * e + 0] = a;
      d[2 * e + 1] = bb;
    }
  }
  const int kbase = hi ? 16 : 0;
#pragma unroll
  for (int p = 0; p < 4; ++p) {   // W1C pairs (k = 2p, 2p+1)
    float* d = wt + ((14 + p) * 64 + ln) * 4;
    d[0] = r3W1[(kbase + 4 * p + 0) * 32 + j] * KE;
    d[1] = r3W1[(kbase + 4 * p + 1) * 32 + j] * KE;
    d[2] = r3W1[(kbase + 4 * p + 2) * 32 + j] * KE;
    d[3] = r3W1[(kbase + 4 * p + 3) * 32 + j] * KE;
  }
  {
    float* d = wt + (18 * 64 + ln) * 4;
    d[0] = r3W0[14 * 32 + j] * KE;                    // WX.x
    d[1] = r3W0[15 * 32 + j] * KE;                    // WX.y
    d[2] = (hi ? r2W0 : r1W0)[j] * KE;                // w0K
    d[3] = (hi ? r2b0 : r1b0)[j] * KE;                // b0K
  }
  {
    float* d = wt + (19 * 64 + ln) * 4;
    d[0] = (hi ? r2b1 : r1b1)[j] * KE;                // b1K
    d[1] = (hi ? r2W2 : r1W2)[j] * (hi ? 0.2f : 0.3f);// w2sc
    d[2] = r3b0[j] * KE;                              // b0CK
    d[3] = r3b1[j] * KE;                              // b1CK
  }
  {
    float* d = wt + (20 * 64 + ln) * 4;
    d[0] = r3W2[j] * 0.2f;                            // w2C02
    d[1] = 0.f; d[2] = 0.f; d[3] = 0.f;
  }
  if (ln == 0) {
    wt[5376] = r1b2[0] * 0.3f;                 // b2sA
    wt[5377] = r2b2[0] * 0.2f;                 // b2sB
    wt[5378] = r3b2[0] * 0.2f - 0.05f;         // b2Cs (folds -F/V*0.5 of dCb)
  }
}

// wave = 1 batch element; lanes 0-31 = net r1 / z duties, 32-63 = r2 / z4.
// grid 4096 -> 16 waves/CU = 4 waves/EU (the validated 790µs structure).
// Weight remats are single COALESCED global_load_dwordx4 from the table
// (L1-hot, vmcnt — overlaps the h-row ds_read lgkmcnt stream).
__global__ __attribute__((amdgpu_flat_work_group_size(64, 64)))
__attribute__((amdgpu_waves_per_eu(4, 4))) void reac_kernel(
    const float* __restrict__ useq,   // [B][T] f32
    const float* __restrict__ xz0,    // [B][26] f32
    const float* __restrict__ wt,     // transposed weight table
    float2* __restrict__ out)         // [B][T] -> (x0,x1) f32
{
  const int lane = threadIdx.x;
  const int j = lane & 31;
  const bool hi = lane >= 32;      // high half = r2 net / z4 duties
  const int b = blockIdx.x;
  const int xaddr = ((lane ^ 32) << 2);   // ds_bpermute partner address

  auto xchg = [&](float v) -> float {
    return __int_as_float(__builtin_amdgcn_ds_bpermute(xaddr, __float_as_int(v)));
  };

  const float4* W4 = (const float4*)wt;   // W4[p*64 + lane], coalesced

  float4 sc0 = W4[18 * 64 + lane];   // WX.x WX.y w0K b0K
  float4 sc1 = W4[19 * 64 + lane];   // b1K w2sc b0CK b1CK
  const float w2C02 = W4[20 * 64 + lane].x;
  const float b2sA = wt[5376];
  const float b2sB = wt[5377];
  const float b2Cs = wt[5378];
  const int kbase = hi ? 16 : 0;

  __shared__ __align__(16) float zs[24];      // z state
  __shared__ __align__(16) float h12[2][32];  // [net][neuron] broadcast
  __shared__ __align__(16) float hR3[3][32];  // [eval: z,z23,z4][neuron]

  float x0 = xz0[b * 26 + 0];
  float x1 = xz0[b * 26 + 1];
  if (!hi && j < 24) zs[j] = xz0[b * 26 + 2 + j];
  CFENCE();

  // 32-wide dot vs LDS h-row; weights: 8 coalesced x4 loads (slots 0-7).
  auto dot32W = [&](const float* hrow, float bias) -> float {
    const float4* hp = (const float4*)hrow;
    float4 w0 = W4[0 * 64 + lane], w1 = W4[1 * 64 + lane];
    float4 w2 = W4[2 * 64 + lane], w3 = W4[3 * 64 + lane];
    float4 w4 = W4[4 * 64 + lane], w5 = W4[5 * 64 + lane];
    float4 w6 = W4[6 * 64 + lane], w7 = W4[7 * 64 + lane];
    float4 x0v = hp[0], x1v = hp[1], x2v = hp[2], x3v = hp[3];
    float4 x4v = hp[4], x5v = hp[5], x6v = hp[6], x7v = hp[7];
    v2f a0 = mk2(bias, 0.f), a1 = mk2(0.f, 0.f);
    v2f a2 = mk2(0.f, 0.f), a3 = mk2(0.f, 0.f);
    a0 = pkfma(mk2(x0v.x, x0v.y), mk2(w0.x, w0.y), a0);
    a1 = pkfma(mk2(x0v.z, x0v.w), mk2(w0.z, w0.w), a1);
    a2 = pkfma(mk2(x1v.x, x1v.y), mk2(w1.x, w1.y), a2);
    a3 = pkfma(mk2(x1v.z, x1v.w), mk2(w1.z, w1.w), a3);
    a0 = pkfma(mk2(x2v.x, x2v.y), mk2(w2.x, w2.y), a0);
    a1 = pkfma(mk2(x2v.z, x2v.w), mk2(w2.z, w2.w), a1);
    a2 = pkfma(mk2(x3v.x, x3v.y), mk2(w3.x, w3.y), a2);
    a3 = pkfma(mk2(x3v.z, x3v.w), mk2(w3.z, w3.w), a3);
    a0 = pkfma(mk2(x4v.x, x4v.y), mk2(w4.x, w4.y), a0);
    a1 = pkfma(mk2(x4v.z, x4v.w), mk2(w4.z, w4.w), a1);
    a2 = pkfma(mk2(x5v.x, x5v.y), mk2(w5.x, w5.y), a2);
    a3 = pkfma(mk2(x5v.z, x5v.w), mk2(w5.z, w5.w), a3);
    a0 = pkfma(mk2(x6v.x, x6v.y), mk2(w6.x, w6.y), a0);
    a1 = pkfma(mk2(x6v.z, x6v.w), mk2(w6.z, w6.w), a1);
    a2 = pkfma(mk2(x7v.x, x7v.y), mk2(w7.x, w7.y), a2);
    a3 = pkfma(mk2(x7v.z, x7v.w), mk2(w7.z, w7.w), a3);
    v2f s = (a0 + a1) + (a2 + a3);
    return s.x + s.y;
  };
  // 16-wide partial dot (k-split r3 layer 1); slots 14-17.
  auto pdot16W = [&](const float* hrow) -> float {
    const float4* hp = (const float4*)hrow;
    float4 wa = W4[14 * 64 + lane], wb = W4[15 * 64 + lane];
    float4 wc = W4[16 * 64 + lane], wd = W4[17 * 64 + lane];
    float4 x0v = hp[0], x1v = hp[1], x2v = hp[2], x3v = hp[3];
    v2f a0 = mk2(0.f, 0.f), a1 = mk2(0.f, 0.f);
    a0 = pkfma(mk2(x0v.x, x0v.y), mk2(wa.x, wa.y), a0);
    a1 = pkfma(mk2(x0v.z, x0v.w), mk2(wa.z, wa.w), a1);
    a0 = pkfma(mk2(x1v.x, x1v.y), mk2(wb.x, wb.y), a0);
    a1 = pkfma(mk2(x1v.z, x1v.w), mk2(wb.z, wb.w), a1);
    a0 = pkfma(mk2(x2v.x, x2v.y), mk2(wc.x, wc.y), a0);
    a1 = pkfma(mk2(x2v.z, x2v.w), mk2(wc.z, wc.w), a1);
    a0 = pkfma(mk2(x3v.x, x3v.y), mk2(wd.x, wd.y), a0);
    a1 = pkfma(mk2(x3v.z, x3v.w), mk2(wd.z, wd.w), a1);
    v2f s = a0 + a1;
    return s.x + s.y;
  };
  // r3 layer-0 over zs: low half A(z), high half A(z4)-prefix; slots 8-13.
  auto r3_l0 = [&](v2f& aaO, v2f& abO) {
    const float4* zp = (const float4*)zs;
    float4 z0 = zp[0], z1 = zp[1], z2 = zp[2], z3 = zp[3];
    float4 u0 = zp[4], u1 = zp[5];
    float4 w8 = W4[8 * 64 + lane], w9 = W4[9 * 64 + lane];
    float4 w10 = W4[10 * 64 + lane], w11 = W4[11 * 64 + lane];
    float4 w12 = W4[12 * 64 + lane], w13 = W4[13 * 64 + lane];
    v2f aa = mk2(sc1.z, 0.f), ab = mk2(0.f, 0.f);   // sc1.z = b0CK
    aa = pkfma(mk2(z0.x, z0.y), mk2(w8.x, w8.y), aa);
    ab = pkfma(mk2(z0.z, z0.w), mk2(w8.z, w8.w), ab);
    aa = pkfma(mk2(z1.x, z1.y), mk2(w9.x, w9.y), aa);
    ab = pkfma(mk2(z1.z, z1.w), mk2(w9.z, w9.w), ab);
    aa = pkfma(mk2(z2.x, z2.y), mk2(w10.x, w10.y), aa);
    ab = pkfma(mk2(z2.z, z2.w), mk2(w10.z, w10.w), ab);
    aa = pkfma(mk2(z3.x, z3.y), mk2(w11.x, w11.y), aa);
    ab = pkfma(mk2(z3.z, z3.w), mk2(w11.z, w11.w), ab);
    aa = pkfma(mk2(u0.x, u0.y), mk2(w12.x, w12.y), aa);
    ab = pkfma(mk2(u0.z, u0.w), mk2(w12.z, w12.w), ab);
    aa = pkfma(mk2(u1.x, u1.y), mk2(w13.x, w13.y), aa);
    ab = pkfma(mk2(u1.z, u1.w), mk2(w13.z, w13.w), ab);
    aaO = aa; abO = ab;
  };
  auto rc1_eval = [&]() -> float {
    float p0 = pdot16W(&hR3[0][kbase]);
    float o0 = p0 + xchg(p0) + sc1.w;                 // + b1CK
    float v = psum4(tanh_pre(o0) * w2C02);
    return (rlane(v, 15) + rlane(v, 31)) + b2Cs;
  };
  auto net_pre = [&](float sxv, float syv) -> float {
    float sv = hi ? syv : sxv;
    return tanh_pre(fmaf(sv, sc0.z, sc0.w));          // w0K, b0K
  };
  auto net_post = [&](float sxv, float syv, float rc_m05, float CafF,
                      float& kx, float& ky) {
    float a = dot32W(&h12[hi][0], sc1.x);             // bias b1K
    float v = psum4(tanh_pre(a) * sc1.y);             // * w2sc
    float ra = (rlane(v, 15) + rlane(v, 31)) + b2sA;  // r1 (uniform)
    float rb = (rlane(v, 47) + rlane(v, 63)) + b2sB;  // r2 (uniform)
    float dCa = fmaf(-0.03f, sxv, CafF) - ra;
    float dCb = fmaf(-0.02f, syv, fmaf(-3.0f, rb, ra) + rc_m05);
    kx = dCa * (1.0f / 0.3f);
    ky = dCb * (1.0f / 0.2f);
  };

  // ---- prologue: pipeline state for t=0 ----
  v2f aa4, ab4;            // carried A(z4)-prefix accumulators (high half)
  float Az;                // carried A(z_t) (low half)
  r3_l0(aa4, ab4);
  {
    v2f s = aa4 + ab4;
    Az = s.x + s.y;
    float h0 = tanh_pre(Az);
    CFENCE();
    if (!hi) hR3[0][j] = h0;
    CFENCE();
  }
  float rc1 = rc1_eval();

  float u = useq[b * TT];

  for (int t = 0; t < TT; ++t) {
    int tn = (t < TT - 1) ? (t + 1) : t;
    float u_nxt = useq[b * TT + tn];   // prefetch, consumed next iter
    float CafF = fmaf(u, 0.05f, 0.05f);

    if (lane == 0) out[b * TT + t] = make_float2(x0, x1);

    // R0: complete z4 eval (1 pkfma) + z23 via layer-0 linearity; stage-1 h.
    ab4 = pkfma(mk2(x0, x1), mk2(sc0.x, sc0.y), ab4);   // WXv
    v2f s4v = aa4 + ab4;
    float A4 = s4v.x + s4v.y;                 // A(z4), high lanes
    float Apart = xchg(hi ? A4 : Az);
    float targ = hi ? A4 : (0.5f * (Az + Apart));   // z23 on low half
    float hh = tanh_pre(targ);
    float h1 = net_pre(x0, x1);
    CFENCE();
    // R1: LDS broadcasts
    hR3[1 + hi][j] = hh;        // low -> h(z23), high -> h(z4)
    h12[hi][j] = h1;
    CFENCE();
    // R2: head finish (rc23, rc4) || stage-1 finish || stage-2 layer-0
    float p1 = pdot16W(&hR3[1][kbase]);
    float p2 = pdot16W(&hR3[2][kbase]);
    float o1 = p1 + xchg(p1) + sc1.w;
    float o2 = p2 + xchg(p2) + sc1.w;
    float vv = psum4(tanh_pre(hi ? o2 : o1) * w2C02);
    float rc23 = (rlane(vv, 15) + rlane(vv, 31)) + b2Cs;
    float rc4  = (rlane(vv, 47) + rlane(vv, 63)) + b2Cs;
    float kx1, ky1;
    net_post(x0, x1, rc1, CafF, kx1, ky1);
    float sx2 = fmaf(kx1, 0.5f, x0), sy2 = fmaf(ky1, 0.5f, x1);
    float h2 = net_pre(sx2, sy2);
    CFENCE();
    // R3
    h12[hi][j] = h2;
    CFENCE();
    // R4a: stage-2 finish || z-shift (reads, fence, masked write)
    float kx2, ky2;
    net_post(sx2, sy2, rc23, CafF, kx2, ky2);
    {
      // zplus = [zs[2:16], x0, x1, zs[17:24], u]
      int src = (j < 14) ? (j + 2) : ((j < 23) ? (j + 1) : 0);
      float zread = zs[src];
      float znew = (j == 14) ? x0 : ((j == 15) ? x1 : ((j == 23) ? u : zread));
      CFENCE();                  // zs reads complete before the write
      if ((!hi) && (j < 24)) zs[j] = znew;
    }
    CFENCE();
    // R4b: r3 layer-0 for t+1 (reads shifted zs) || stage-3 layer-0
    r3_l0(aa4, ab4);
    {
      v2f sv2 = aa4 + ab4;
      Az = sv2.x + sv2.y;                  // A(z_{t+1}) on low lanes
      float h0n = tanh_pre(Az);
      if (!hi) hR3[0][j] = h0n;            // h(z_{t+1})
    }
    float sx3 = fmaf(kx2, 0.5f, x0), sy3 = fmaf(ky2, 0.5f, x1);
    float h3 = net_pre(sx3, sy3);
    CFENCE();
    // R5
    h12[hi][j] = h3;
    CFENCE();
    // R6: stage-3 finish || rc1 for t+1 || stage-4 layer-0
    float kx3, ky3;
    net_post(sx3, sy3, rc23, CafF, kx3, ky3);
    rc1 = rc1_eval();
    float sx4 = x0 + kx3, sy4 = x1 + ky3;
    float h4 = net_pre(sx4, sy4);
    CFENCE();
    // R7
    h12[hi][j] = h4;
    CFENCE();
    // R8: stage-4 finish, state update
    float kx4, ky4;
    net_post(sx4, sy4, rc4, CafF, kx4, ky4);
    x0 += (kx1 + 2.0f * (kx2 + kx3) + kx4) * (1.0f / 6.0f);
    x1 += (ky1 + 2.0f * (ky2 + ky3) + ky4) * (1.0f / 6.0f);
    u = u_nxt;
    CFENCE();
  }
}

extern "C" void kernel_launch(void* const* d_in, const int* in_sizes, int n_in,
                              void* d_out, int out_size, void* d_ws, size_t ws_size,
                              hipStream_t stream) {
  const float* p[20];
  for (int i = 0; i < 20; ++i) p[i] = (const float*)d_in[i];
  float* wtab = (float*)d_ws;
  wtrans_kernel<<<dim3(1), dim3(64), 0, stream>>>(
      p[2], p[3], p[4], p[5], p[6], p[7], p[8], p[9], p[10], p[11],
      p[12], p[13], p[14], p[15], p[16], p[17], p[18], p[19], wtab);
  reac_kernel<<<dim3(4096), dim3(64), 0, stream>>>(
      p[0], p[1], wtab, (float2*)d_out);
}

// Round 10
// 843.470 us; speedup vs baseline: 5.1055x; 1.7421x over previous
//
#include <hip/hip_runtime.h>

#define DEVINL static __device__ __forceinline__
// Same-wave LDS ordering: compiler reorder fence only (validated r10/r12).
#define CFENCE() asm volatile("" ::: "memory")

typedef float v2f __attribute__((ext_vector_type(2)));

DEVINL v2f mk2(float a, float b) { v2f r; r.x = a; r.y = b; return r; }
DEVINL v2f pkfma(v2f a, v2f b, v2f c) { return __builtin_elementwise_fma(a, b, c); }

constexpr float KE = 2.885390081777927f;   // 2*log2(e)

#if __has_builtin(__builtin_amdgcn_exp2f)
DEVINL float exp2_fast(float x) { return __builtin_amdgcn_exp2f(x); }
#else
DEVINL float exp2_fast(float x) { return __expf(x * 0.6931471805599453f); }
#endif

// tanh(x) with t = x*2*log2(e) pre-folded into weights: 1 - 2/(2^t+1).
DEVINL float tanh_pre(float t) {
  float e = exp2_fast(t);
  return 1.0f - 2.0f * __builtin_amdgcn_rcpf(e + 1.0f);
}

template <int CTRL>
DEVINL float dpp_add(float v) {
  int t = __builtin_amdgcn_update_dpp(0, __float_as_int(v), CTRL, 0xF, 0xF, true);
  return v + __int_as_float(t);
}
DEVINL float rlane(float v, int l) {
  return __int_as_float(__builtin_amdgcn_readlane(__float_as_int(v), l));
}
// 4-stage row-local DPP partial sums; 32-sums via readlane pairs
// (commutative pair-add, bit-identical to row_bcast15 variant; validated).
DEVINL float psum4(float v) {
  v = dpp_add<0xB1>(v);    // quad_perm [1,0,3,2]
  v = dpp_add<0x4E>(v);    // quad_perm [2,3,0,1]
  v = dpp_add<0x141>(v);   // row_half_mirror
  v = dpp_add<0x140>(v);   // row_mirror -> 16-sums per row
  return v;
}

// 32-wide dot vs an LDS row (uniform address per half), packed fp32.
DEVINL float dot32(const float* hrow, const v2f* W, float bias) {
  const float4* hp = (const float4*)hrow;
  v2f a0 = mk2(bias, 0.f), a1 = mk2(0.f, 0.f);
  v2f a2 = mk2(0.f, 0.f), a3 = mk2(0.f, 0.f);
#pragma unroll
  for (int q = 0; q < 8; q += 2) {
    float4 x = hp[q], y = hp[q + 1];
    a0 = pkfma(mk2(x.x, x.y), W[2 * q + 0], a0);
    a1 = pkfma(mk2(x.z, x.w), W[2 * q + 1], a1);
    a2 = pkfma(mk2(y.x, y.y), W[2 * q + 2], a2);
    a3 = pkfma(mk2(y.z, y.w), W[2 * q + 3], a3);
  }
  v2f s = (a0 + a1) + (a2 + a3);
  return s.x + s.y;
}
// 16-wide partial dot (k-split r3 layer 1), packed fp32.
DEVINL float pdot16(const float* hrow, const v2f* W) {
  const float4* hp = (const float4*)hrow;
  v2f a0 = mk2(0.f, 0.f), a1 = mk2(0.f, 0.f);
  float4 x = hp[0], y = hp[1];
  a0 = pkfma(mk2(x.x, x.y), W[0], a0);
  a1 = pkfma(mk2(x.z, x.w), W[1], a1);
  a0 = pkfma(mk2(y.x, y.y), W[2], a0);
  a1 = pkfma(mk2(y.z, y.w), W[3], a1);
  x = hp[2]; y = hp[3];
  a0 = pkfma(mk2(x.x, x.y), W[4], a0);
  a1 = pkfma(mk2(x.z, x.w), W[5], a1);
  a0 = pkfma(mk2(y.x, y.y), W[6], a0);
  a1 = pkfma(mk2(y.z, y.w), W[7], a1);
  v2f s = a0 + a1;
  return s.x + s.y;
}

constexpr int TT = 256;

// wave = 1 batch element; lanes 0-31 = net r1/z duties, 32-63 = r2/z4.
// grid 4096 -> 16 waves/CU = 4 waves/EU (the validated 790µs structure).
// R10 restructure: z-shift hoisted to R0 with ping-pong zs buffers;
// next-step r3 layer-0 + h(z') ride inside the fat stage-1 region; rc1
// moved to the stage-2 region. 12 fences/step -> 9; no extra LDS round
// trips between stages 2 and 3. All arithmetic bit-identical to R1.
__global__ __attribute__((amdgpu_flat_work_group_size(64, 64)))
__attribute__((amdgpu_waves_per_eu(4, 4))) void reac_kernel(
    const float* __restrict__ useq,   // [B][T] f32
    const float* __restrict__ xz0,    // [B][26] f32
    const float* __restrict__ r1W0, const float* __restrict__ r1b0,
    const float* __restrict__ r1W1, const float* __restrict__ r1b1,
    const float* __restrict__ r1W2, const float* __restrict__ r1b2,
    const float* __restrict__ r2W0, const float* __restrict__ r2b0,
    const float* __restrict__ r2W1, const float* __restrict__ r2b1,
    const float* __restrict__ r2W2, const float* __restrict__ r2b2,
    const float* __restrict__ r3W0, const float* __restrict__ r3b0,
    const float* __restrict__ r3W1, const float* __restrict__ r3b1,
    const float* __restrict__ r3W2, const float* __restrict__ r3b2,
    float2* __restrict__ out)         // [B][T] -> (x0,x1) f32
{
  const int lane = threadIdx.x;
  const int j = lane & 31;
  const bool hi = lane >= 32;      // high half = r2 net / z4 duties
  const int b = blockIdx.x;
  const int xaddr = ((lane ^ 32) << 2);   // ds_bpermute partner address

  auto xchg = [&](float v) -> float {
    return __int_as_float(__builtin_amdgcn_ds_bpermute(xaddr, __float_as_int(v)));
  };

  // ---- per-half net weights (column j), tanh prescale KE folded in ----
  const float* W0p = hi ? r2W0 : r1W0;
  const float* B0p = hi ? r2b0 : r1b0;
  const float* W1p = hi ? r2W1 : r1W1;
  const float* B1p = hi ? r2b1 : r1b1;
  const float* W2p = hi ? r2W2 : r1W2;
  const float sc = hi ? 0.2f : 0.3f;
  float w0K = W0p[j] * KE, b0K = B0p[j] * KE;
  float b1K = B1p[j] * KE;
  float w2sc = W2p[j] * sc;

  v2f W1v[16];
#pragma unroll
  for (int k = 0; k < 16; ++k)
    W1v[k] = mk2(W1p[(2 * k) * 32 + j] * KE, W1p[(2 * k + 1) * 32 + j] * KE);

  // r3 layer-0 weights, per-half arrangement over the 12 aligned z-pairs:
  //   low  (A(z)):      pair m -> rows (2m, 2m+1)
  //   high (A(z4) pre): pair 0 unused (0); pairs 1..7 -> rows (2m-2, 2m-1);
  //                     pairs 8..11 (upseq) as low. x-pair rows (14,15)
  //                     deferred to WXv, applied once x is live.
  v2f W0Cv[12];
#pragma unroll
  for (int m = 0; m < 12; ++m) {
    int r = (hi && m >= 1 && m <= 7) ? (2 * m - 2) : (2 * m);
    v2f w = mk2(r3W0[r * 32 + j] * KE, r3W0[(r + 1) * 32 + j] * KE);
    if (hi && m == 0) w = mk2(0.f, 0.f);
    W0Cv[m] = w;
  }
  v2f WXv = mk2(r3W0[14 * 32 + j] * KE, r3W0[15 * 32 + j] * KE);

  const int kbase = hi ? 16 : 0;
  v2f W1Cv[8];
#pragma unroll
  for (int k = 0; k < 8; ++k)
    W1Cv[k] = mk2(r3W1[(kbase + 2 * k) * 32 + j] * KE,
                  r3W1[(kbase + 2 * k + 1) * 32 + j] * KE);
  float b0CK = r3b0[j] * KE, b1CK = r3b1[j] * KE;
  float w2C02 = r3W2[j] * 0.2f;

  // wave-uniform scalars (biases folded with output scales)
  const float b2sA = r1b2[0] * 0.3f;
  const float b2sB = r2b2[0] * 0.2f;
  const float b2Cs = r3b2[0] * 0.2f - 0.05f;   // folds -F/V*0.5 of dCb

  __shared__ __align__(16) float zs2[2][24];  // ping-pong z state
  __shared__ __align__(16) float h12[2][32];  // [net][neuron] broadcast
  __shared__ __align__(16) float hR3[3][32];  // [eval: z,z23,z4][neuron]

  float* zsC = &zs2[0][0];   // holds z_t
  float* zsN = &zs2[1][0];   // receives z_{t+1}

  float x0 = xz0[b * 26 + 0];
  float x1 = xz0[b * 26 + 1];
  if (!hi && j < 24) zsC[j] = xz0[b * 26 + 2 + j];
  CFENCE();

  // r3 layer-0 over zp: low half accumulates A(z), high half A(z4)-prefix.
  auto r3_l0 = [&](const float* zp_, v2f& aaO, v2f& abO) {
    const float4* zp = (const float4*)zp_;
    float4 z0 = zp[0], z1 = zp[1], z2 = zp[2], z3 = zp[3];
    float4 u0 = zp[4], u1 = zp[5];
    v2f aa = mk2(b0CK, 0.f), ab = mk2(0.f, 0.f);
    aa = pkfma(mk2(z0.x, z0.y), W0Cv[0], aa);
    ab = pkfma(mk2(z0.z, z0.w), W0Cv[1], ab);
    aa = pkfma(mk2(z1.x, z1.y), W0Cv[2], aa);
    ab = pkfma(mk2(z1.z, z1.w), W0Cv[3], ab);
    aa = pkfma(mk2(z2.x, z2.y), W0Cv[4], aa);
    ab = pkfma(mk2(z2.z, z2.w), W0Cv[5], ab);
    aa = pkfma(mk2(z3.x, z3.y), W0Cv[6], aa);
    ab = pkfma(mk2(z3.z, z3.w), W0Cv[7], ab);
    aa = pkfma(mk2(u0.x, u0.y), W0Cv[8], aa);
    ab = pkfma(mk2(u0.z, u0.w), W0Cv[9], ab);
    aa = pkfma(mk2(u1.x, u1.y), W0Cv[10], aa);
    ab = pkfma(mk2(u1.z, u1.w), W0Cv[11], ab);
    aaO = aa; abO = ab;
  };
  auto rc1_eval = [&]() -> float {
    float p0 = pdot16(&hR3[0][kbase], W1Cv);
    float o0 = p0 + xchg(p0) + b1CK;
    float v = psum4(tanh_pre(o0) * w2C02);
    return (rlane(v, 15) + rlane(v, 31)) + b2Cs;
  };
  auto net_pre = [&](float sxv, float syv) -> float {
    float sv = hi ? syv : sxv;
    return tanh_pre(fmaf(sv, w0K, b0K));
  };
  auto net_post = [&](float sxv, float syv, float rc_m05, float CafF,
                      float& kx, float& ky) {
    float a = dot32(&h12[hi][0], W1v, b1K);
    float v = psum4(tanh_pre(a) * w2sc);
    float ra = (rlane(v, 15) + rlane(v, 31)) + b2sA;   // r1 (uniform)
    float rb = (rlane(v, 47) + rlane(v, 63)) + b2sB;   // r2 (uniform)
    float dCa = fmaf(-0.03f, sxv, CafF) - ra;
    float dCb = fmaf(-0.02f, syv, fmaf(-3.0f, rb, ra) + rc_m05);
    kx = dCa * (1.0f / 0.3f);
    ky = dCb * (1.0f / 0.2f);
  };

  // ---- prologue: pipeline state for t=0 ----
  v2f aa4, ab4;            // carried A(z4)-prefix accumulators (high half)
  float Az;                // carried A(z_t) (low half)
  r3_l0(zsC, aa4, ab4);
  {
    v2f s = aa4 + ab4;
    Az = s.x + s.y;
    float h0 = tanh_pre(Az);
    CFENCE();
    if (!hi) hR3[0][j] = h0;
    CFENCE();
  }
  float rc1 = rc1_eval();

  float u = useq[b * TT];

  for (int t = 0; t < TT; ++t) {
    int tn = (t < TT - 1) ? (t + 1) : t;
    float u_nxt = useq[b * TT + tn];   // prefetch, consumed next iter
    float CafF = fmaf(u, 0.05f, 0.05f);

    if (lane == 0) out[b * TT + t] = make_float2(x0, x1);

    // R0: z4 completion (1 pkfma) + z23 via linearity; stage-1 hidden;
    //     z-shift value (z_{t+1} fully known from x_t, u_t, z_t).
    ab4 = pkfma(mk2(x0, x1), WXv, ab4);
    v2f s4v = aa4 + ab4;
    float A4 = s4v.x + s4v.y;                 // A(z4), high lanes
    float Apart = xchg(hi ? A4 : Az);
    float targ = hi ? A4 : (0.5f * (Az + Apart));   // z23 on low half
    float hh = tanh_pre(targ);
    float h1 = net_pre(x0, x1);
    int src = (j < 14) ? (j + 2) : ((j < 23) ? (j + 1) : 0);
    float zread = zsC[src];
    float znew = (j == 14) ? x0 : ((j == 15) ? x1 : ((j == 23) ? u : zread));
    CFENCE();
    // F1: LDS writes (h broadcasts + z_{t+1} into the OTHER buffer)
    hR3[1 + hi][j] = hh;        // low -> h(z23), high -> h(z4)
    h12[hi][j] = h1;
    if (!hi && j < 24) zsN[j] = znew;
    CFENCE();
    // R2 (fat): head finish (rc23, rc4) || stage-1 finish || next-step
    //           r3 layer-0 over zsN || stage-2 hidden
    float p1 = pdot16(&hR3[1][kbase], W1Cv);
    float p2 = pdot16(&hR3[2][kbase], W1Cv);
    float o1 = p1 + xchg(p1) + b1CK;
    float o2 = p2 + xchg(p2) + b1CK;
    float vv = psum4(tanh_pre(hi ? o2 : o1) * w2C02);
    float rc23 = (rlane(vv, 15) + rlane(vv, 31)) + b2Cs;
    float rc4  = (rlane(vv, 47) + rlane(vv, 63)) + b2Cs;
    float kx1, ky1;
    net_post(x0, x1, rc1, CafF, kx1, ky1);
    r3_l0(zsN, aa4, ab4);                  // A(z_{t+1}) pieces
    v2f sv2 = aa4 + ab4;
    Az = sv2.x + sv2.y;                    // A(z_{t+1}) on low lanes
    float h0n = tanh_pre(Az);
    float sx2 = fmaf(kx1, 0.5f, x0), sy2 = fmaf(ky1, 0.5f, x1);
    float h2 = net_pre(sx2, sy2);
    CFENCE();
    // F2
    h12[hi][j] = h2;
    if (!hi) hR3[0][j] = h0n;              // h(z_{t+1})
    CFENCE();
    // R4: stage-2 finish || rc1 for t+1
    float kx2, ky2;
    net_post(sx2, sy2, rc23, CafF, kx2, ky2);
    rc1 = rc1_eval();
    float sx3 = fmaf(kx2, 0.5f, x0), sy3 = fmaf(ky2, 0.5f, x1);
    float h3 = net_pre(sx3, sy3);
    CFENCE();
    // F3
    h12[hi][j] = h3;
    CFENCE();
    // R6: stage-3 finish
    float kx3, ky3;
    net_post(sx3, sy3, rc23, CafF, kx3, ky3);
    float sx4 = x0 + kx3, sy4 = x1 + ky3;
    float h4 = net_pre(sx4, sy4);
    CFENCE();
    // F4
    h12[hi][j] = h4;
    CFENCE();
    // R8: stage-4 finish, state update, buffer swap
    float kx4, ky4;
    net_post(sx4, sy4, rc4, CafF, kx4, ky4);
    x0 += (kx1 + 2.0f * (kx2 + kx3) + kx4) * (1.0f / 6.0f);
    x1 += (ky1 + 2.0f * (ky2 + ky3) + ky4) * (1.0f / 6.0f);
    u = u_nxt;
    float* ztmp = zsC; zsC = zsN; zsN = ztmp;
    CFENCE();
  }
}

extern "C" void kernel_launch(void* const* d_in, const int* in_sizes, int n_in,
                              void* d_out, int out_size, void* d_ws, size_t ws_size,
                              hipStream_t stream) {
  const float* p[20];
  for (int i = 0; i < 20; ++i) p[i] = (const float*)d_in[i];
  reac_kernel<<<dim3(4096), dim3(64), 0, stream>>>(
      p[0], p[1], p[2], p[3], p[4], p[5], p[6], p[7], p[8], p[9], p[10],
      p[11], p[12], p[13], p[14], p[15], p[16], p[17], p[18], p[19],
      (float2*)d_out);
}